// Round 1
// baseline (1004.825 us; speedup 1.0000x reference)
//
#include <hip/hip_runtime.h>
#include <math.h>

#define NEG_BIG   (-4294967296.0f)   /* float32(-2^32+1) */
#define NEG_INF_F (-__builtin_inff())

/* ---- workspace layout (floats) ---- */
#define WS_A    0        /* [80][64]  w1[:,64:128] - w1[:,128:192] */
#define WS_S    5120     /* [80][64]  w1[:,0:64]   + w1[:,128:192] */
#define WS_W1T  10240    /* [288][200] mlp_w1 transposed           */
#define WS_W2T  67840    /* [200][80]  mlp_w2 transposed           */
#define WS_W3T  83840    /* [80][2]    mlp_w3 transposed           */

__global__ __launch_bounds__(256) void prep_kernel(
    const float* __restrict__ att_w1,
    const float* __restrict__ mlp_w1,
    const float* __restrict__ mlp_w2,
    const float* __restrict__ mlp_w3,
    float* __restrict__ ws)
{
    int idx = blockIdx.x * 256 + threadIdx.x;
    if (idx < 5120) {
        int h = idx >> 6, j = idx & 63;
        ws[WS_A + idx] = att_w1[h*256 + 64 + j] - att_w1[h*256 + 128 + j];
        ws[WS_S + idx] = att_w1[h*256 + j]      + att_w1[h*256 + 128 + j];
    } else if (idx < 62720) {
        int r = idx - 5120;            /* r = k*200 + t */
        int k = r / 200, t = r - k*200;
        ws[WS_W1T + r] = mlp_w1[t*288 + k];
    } else if (idx < 78720) {
        int r = idx - 62720;           /* r = k*80 + g */
        int k = r / 80, g = r - k*80;
        ws[WS_W2T + r] = mlp_w2[g*200 + k];
    } else if (idx < 78880) {
        int r = idx - 78720;           /* r = k*2 + o */
        int k = r >> 1, o = r & 1;
        ws[WS_W3T + r] = mlp_w3[o*80 + k];
    }
}

__device__ __forceinline__ float fsigmoid(float x) {
    return __fdividef(1.0f, 1.0f + __expf(-x));
}

__global__ __launch_bounds__(256, 2) void din_kernel(
    const int* __restrict__ uid, const int* __restrict__ gid, const int* __restrict__ cid,
    const int* __restrict__ gid_his, const int* __restrict__ cid_his, const int* __restrict__ masks,
    const float* __restrict__ user_emb, const float* __restrict__ good_emb, const float* __restrict__ cat_emb,
    const float* __restrict__ att_w1, const float* __restrict__ att_b1,
    const float* __restrict__ att_w2, const float* __restrict__ att_b2,
    const float* __restrict__ att_w3, const float* __restrict__ att_b3,
    const float* __restrict__ mlp_b1, const float* __restrict__ mlp_b2, const float* __restrict__ mlp_b3,
    const float* __restrict__ pa1, const float* __restrict__ pa2,
    const float* __restrict__ ws, float* __restrict__ out)
{
    __shared__ float q_sh[64];
    __shared__ float c0_sh[80];
    __shared__ float beh_sh[200*65];   /* stride 65: conflict-free column reads */
    __shared__ float sp_sh[256];
    __shared__ float redA[256];
    __shared__ float redU[256];
    __shared__ float scal_sh[2];
    __shared__ float x_sh[288];
    __shared__ float h1_sh[200];
    __shared__ float h2_sh[80];

    const int b   = blockIdx.x;
    const int tid = threadIdx.x;

    /* ---- Phase 0: issue all behavior-gather loads into registers ---- */
    float4 gbuf[13];
    #pragma unroll
    for (int it = 0; it < 13; ++it) {
        int idx = it*256 + tid;
        if (idx < 3200) {
            int l = idx >> 4, c = idx & 15;
            const float* src = (c < 8)
                ? (good_emb + (size_t)gid_his[b*200 + l]*32 + (c & 7)*4)
                : (cat_emb  + (size_t)cid_his[b*200 + l]*32 + (c & 7)*4);
            gbuf[it] = *(const float4*)src;
        }
    }
    /* query = [good_emb[gid], cat_emb[cid]] */
    if (tid < 64) {
        q_sh[tid] = (tid < 32) ? good_emb[(size_t)gid[b]*32 + tid]
                               : cat_emb[(size_t)cid[b]*32 + (tid - 32)];
    }
    __syncthreads();

    /* ---- Phase 1: beh -> LDS; c0[h] = b1[h] + sum_j q_j*(W1[h,j]+W1[h,128+j]) ---- */
    #pragma unroll
    for (int it = 0; it < 13; ++it) {
        int idx = it*256 + tid;
        if (idx < 3200) {
            int l = idx >> 4, c = idx & 15;
            float* dst = &beh_sh[l*65 + c*4];
            dst[0] = gbuf[it].x; dst[1] = gbuf[it].y; dst[2] = gbuf[it].z; dst[3] = gbuf[it].w;
        }
    }
    if (tid < 80) {
        const float* Sw = ws + WS_S + tid*64;
        float u0 = 0.f, u1 = 0.f;
        #pragma unroll
        for (int j = 0; j < 64; j += 2) {
            u0 += q_sh[j]   * Sw[j];
            u1 += q_sh[j+1] * Sw[j+1];
        }
        c0_sh[tid] = att_b1[tid] + u0 + u1;
    }
    __syncthreads();

    /* ---- Phase 2: per-l attention MLP (lane = l) ---- */
    const int lr = (tid < 200) ? tid : 199;
    float beh_r[64], qb_r[64];
    #pragma unroll
    for (int j = 0; j < 64; ++j) {
        beh_r[j] = beh_sh[lr*65 + j];
        qb_r[j]  = q_sh[j] * beh_r[j];
    }

    float acc2[40];
    #pragma unroll
    for (int g = 0; g < 40; ++g) acc2[g] = att_b2[g];

    const float* Aw = ws + WS_A;
    #pragma unroll 1
    for (int h0 = 0; h0 < 80; h0 += 4) {
        float r0 = 0.f, r1 = 0.f, r2 = 0.f, r3 = 0.f;   /* beh * A terms  */
        float t0 = 0.f, t1 = 0.f, t2 = 0.f, t3 = 0.f;   /* (q*beh) * Wp terms */
        const float* Ap = Aw + h0*64;
        const float* Wp = att_w1 + h0*256 + 192;
        #pragma unroll
        for (int j = 0; j < 64; ++j) {
            float bv = beh_r[j], qv = qb_r[j];
            r0 += bv * Ap[j];        t0 += qv * Wp[j];
            r1 += bv * Ap[64  + j];  t1 += qv * Wp[256 + j];
            r2 += bv * Ap[128 + j];  t2 += qv * Wp[512 + j];
            r3 += bv * Ap[192 + j];  t3 += qv * Wp[768 + j];
        }
        float s0 = fsigmoid(c0_sh[h0+0] + r0 + t0);
        float s1 = fsigmoid(c0_sh[h0+1] + r1 + t1);
        float s2 = fsigmoid(c0_sh[h0+2] + r2 + t2);
        float s3 = fsigmoid(c0_sh[h0+3] + r3 + t3);
        const float* W2p = att_w2 + h0;
        #pragma unroll
        for (int g = 0; g < 40; ++g) {
            acc2[g] += s0*W2p[g*80+0] + s1*W2p[g*80+1] + s2*W2p[g*80+2] + s3*W2p[g*80+3];
        }
    }

    /* layer 3 */
    float sv = att_b3[0];
    #pragma unroll
    for (int g = 0; g < 40; ++g) sv += fsigmoid(acc2[g]) * att_w3[g];

    /* ---- Phase 3: masked softmax over l ---- */
    int mk = (tid < 200) ? masks[b*200 + tid] : 0;
    float s_masked = (mk != 0) ? sv : NEG_BIG;
    sp_sh[tid] = (tid < 200) ? s_masked : NEG_INF_F;
    __syncthreads();

    if (tid < 64) {
        float m = fmaxf(fmaxf(sp_sh[tid], sp_sh[tid+64]), fmaxf(sp_sh[tid+128], sp_sh[tid+192]));
        #pragma unroll
        for (int off = 32; off > 0; off >>= 1) m = fmaxf(m, __shfl_down(m, off));
        if (tid == 0) scal_sh[0] = m;
    }
    __syncthreads();
    float mx = scal_sh[0];
    float ev = (tid < 200) ? __expf(s_masked - mx) : 0.0f;
    sp_sh[tid] = ev;
    __syncthreads();
    if (tid < 64) {
        float s = (sp_sh[tid] + sp_sh[tid+64]) + (sp_sh[tid+128] + sp_sh[tid+192]);
        #pragma unroll
        for (int off = 32; off > 0; off >>= 1) s += __shfl_down(s, off);
        if (tid == 0) scal_sh[1] = s;
    }
    __syncthreads();

    /* ---- Phase 4: pooling att = sum w*beh (unnormalized, divide at end), ubs = sum beh ---- */
    {
        int j  = tid & 63, qq = tid >> 6;
        float accA = 0.f, accU = 0.f;
        int l0 = qq * 50;
        #pragma unroll 10
        for (int l = l0; l < l0 + 50; ++l) {
            float bv = beh_sh[l*65 + j];
            accA += sp_sh[l] * bv;
            accU += bv;
        }
        redA[tid] = accA;
        redU[tid] = accU;
    }
    __syncthreads();

    float inv = 1.0f / scal_sh[1];
    if (tid < 64) {
        float att = ((redA[tid] + redA[tid+64]) + (redA[tid+128] + redA[tid+192])) * inv;
        float ub  =  (redU[tid] + redU[tid+64]) + (redU[tid+128] + redU[tid+192]);
        x_sh[32  + tid] = q_sh[tid];
        x_sh[96  + tid] = ub;
        x_sh[160 + tid] = ub * q_sh[tid];
        x_sh[224 + tid] = att;
    }
    if (tid >= 64 && tid < 96) {
        x_sh[tid - 64] = user_emb[(size_t)uid[b]*32 + (tid - 64)];
    }
    __syncthreads();

    /* ---- Phase 5: final MLP 288 -> 200 -> 80 -> 2 ---- */
    const float* w1T = ws + WS_W1T;
    if (tid < 200) {
        float A0 = 0.f, A1 = 0.f, A2 = 0.f, A3 = 0.f;
        #pragma unroll 4
        for (int k = 0; k < 288; k += 4) {
            A0 += x_sh[k+0] * w1T[(k+0)*200 + tid];
            A1 += x_sh[k+1] * w1T[(k+1)*200 + tid];
            A2 += x_sh[k+2] * w1T[(k+2)*200 + tid];
            A3 += x_sh[k+3] * w1T[(k+3)*200 + tid];
        }
        float acc = ((A0+A1) + (A2+A3)) + mlp_b1[tid];
        h1_sh[tid] = (acc >= 0.f) ? acc : pa1[tid]*acc;
    }
    __syncthreads();
    const float* w2T = ws + WS_W2T;
    if (tid < 80) {
        float A0 = 0.f, A1 = 0.f, A2 = 0.f, A3 = 0.f;
        #pragma unroll 4
        for (int k = 0; k < 200; k += 4) {
            A0 += h1_sh[k+0] * w2T[(k+0)*80 + tid];
            A1 += h1_sh[k+1] * w2T[(k+1)*80 + tid];
            A2 += h1_sh[k+2] * w2T[(k+2)*80 + tid];
            A3 += h1_sh[k+3] * w2T[(k+3)*80 + tid];
        }
        float acc = ((A0+A1) + (A2+A3)) + mlp_b2[tid];
        h2_sh[tid] = (acc >= 0.f) ? acc : pa2[tid]*acc;
    }
    __syncthreads();
    if (tid < 2) {
        const float* w3T = ws + WS_W3T;
        float acc = mlp_b3[tid];
        #pragma unroll 8
        for (int k = 0; k < 80; ++k) acc += h2_sh[k] * w3T[k*2 + tid];
        out[b*2 + tid] = acc;
    }
}

extern "C" void kernel_launch(void* const* d_in, const int* in_sizes, int n_in,
                              void* d_out, int out_size, void* d_ws, size_t ws_size,
                              hipStream_t stream) {
    const int*   uid      = (const int*)d_in[0];
    const int*   gid      = (const int*)d_in[1];
    const int*   cid      = (const int*)d_in[2];
    const int*   gid_his  = (const int*)d_in[3];
    const int*   cid_his  = (const int*)d_in[4];
    const int*   masks    = (const int*)d_in[5];
    const float* user_emb = (const float*)d_in[6];
    const float* good_emb = (const float*)d_in[7];
    const float* cat_emb  = (const float*)d_in[8];
    const float* att_w1   = (const float*)d_in[9];
    const float* att_b1   = (const float*)d_in[10];
    const float* att_w2   = (const float*)d_in[11];
    const float* att_b2   = (const float*)d_in[12];
    const float* att_w3   = (const float*)d_in[13];
    const float* att_b3   = (const float*)d_in[14];
    const float* mlp_w1   = (const float*)d_in[15];
    const float* mlp_b1   = (const float*)d_in[16];
    const float* mlp_w2   = (const float*)d_in[17];
    const float* mlp_b2   = (const float*)d_in[18];
    const float* mlp_w3   = (const float*)d_in[19];
    const float* mlp_b3   = (const float*)d_in[20];
    const float* pa1      = (const float*)d_in[21];
    const float* pa2      = (const float*)d_in[22];
    float* ws  = (float*)d_ws;
    float* outp = (float*)d_out;

    hipLaunchKernelGGL(prep_kernel, dim3(309), dim3(256), 0, stream,
                       att_w1, mlp_w1, mlp_w2, mlp_w3, ws);
    hipLaunchKernelGGL(din_kernel, dim3(4096), dim3(256), 0, stream,
                       uid, gid, cid, gid_his, cid_his, masks,
                       user_emb, good_emb, cat_emb,
                       att_w1, att_b1, att_w2, att_b2, att_w3, att_b3,
                       mlp_b1, mlp_b2, mlp_b3, pa1, pa2, ws, outp);
}

// Round 2
// 307.634 us; speedup vs baseline: 3.2663x; 3.2663x over previous
//
#include <hip/hip_runtime.h>
#include <math.h>

typedef unsigned short u16;
typedef unsigned int u32;
typedef __attribute__((ext_vector_type(8))) short short8;
typedef __attribute__((ext_vector_type(8))) float f32x8;
typedef __attribute__((ext_vector_type(4))) float f32x4;
typedef __attribute__((ext_vector_type(2))) unsigned int uint2v;

#define NEG_BIG   (-4294967296.0f)   /* float32(-2^32+1) */
#define NEG_INF_F (-__builtin_inff())

/* ---- workspace layout (float offsets) ---- */
#define WS_S    0        /* [80][64] f32: w1[:,0:64]+w1[:,128:192] (for c0) */
#define WS_W1T  5120     /* [288][200] f32 mlp_w1^T */
#define WS_W2T  62720    /* [200][80]  f32 mlp_w2^T */
#define WS_W3T  78720    /* [80][2]    f32 mlp_w3^T */
#define WS_W3P  78880    /* [48] f32 att_w3 zero-padded */
#define WS_WF1F 78928    /* 10240 bf16 = 5120 float-slots: W1cat frags [5 nt][4 ks][64 lane][8] */
#define WS_WF2F 84048    /* 4608 bf16 = 2304 float-slots: W2cat frags [3 nt][3 ks][64 lane][8] */
/* total 86352 floats = 345.4 KB */

__device__ __forceinline__ u16 f2bf(float f) {
    union { float f; u32 u; } v; v.f = f;
    u32 r = v.u + 0x7FFFu + ((v.u >> 16) & 1u);
    return (u16)(r >> 16);
}
__device__ __forceinline__ float bf2f(u16 h) {
    union { u32 u; float f; } v; v.u = ((u32)h) << 16;
    return v.f;
}
__device__ __forceinline__ float fsigmoid(float x) {
    return __fdividef(1.0f, 1.0f + __expf(-x));
}
__device__ __forceinline__ short8 mulqf(short8 a, f32x8 qf) {
    short8 r;
    #pragma unroll
    for (int j = 0; j < 8; ++j) r[j] = (short)f2bf(bf2f((u16)a[j]) * qf[j]);
    return r;
}
__device__ __forceinline__ f32x4 mfma16(short8 a, short8 b, f32x4 c) {
    return __builtin_amdgcn_mfma_f32_16x16x32_bf16(a, b, c, 0, 0, 0);
}

__global__ __launch_bounds__(256) void prep_kernel(
    const float* __restrict__ att_w1,
    const float* __restrict__ att_w2,
    const float* __restrict__ att_w3,
    const float* __restrict__ mlp_w1,
    const float* __restrict__ mlp_w2,
    const float* __restrict__ mlp_w3,
    float* __restrict__ ws)
{
    int idx = blockIdx.x * 256 + threadIdx.x;
    if (idx < 5120) {
        int h = idx >> 6, j = idx & 63;
        ws[WS_S + idx] = att_w1[h*256 + j] + att_w1[h*256 + 128 + j];
    } else if (idx < 62720) {
        int r = idx - 5120;            /* r = k*200 + t */
        int k = r / 200, t = r - k*200;
        ws[WS_W1T + r] = mlp_w1[t*288 + k];
    } else if (idx < 78720) {
        int r = idx - 62720;           /* r = k*80 + g */
        int k = r / 80, g = r - k*80;
        ws[WS_W2T + r] = mlp_w2[g*200 + k];
    } else if (idx < 78880) {
        int r = idx - 78720;           /* r = k*2 + o */
        int k = r >> 1, o = r & 1;
        ws[WS_W3T + r] = mlp_w3[o*80 + k];
    } else if (idx < 78928) {
        int g = idx - 78880;
        ws[WS_W3P + g] = (g < 40) ? att_w3[g] : 0.0f;
    } else if (idx < 89168) {
        /* W1cat fragments: Xcat(200x128) @ W1cat(128x80)
           k<64: beh rows -> w1[:,64:128]-w1[:,128:192]; k>=64: q*beh -> w1[:,192:256] */
        int e  = idx - 78928;
        int nt = e >> 11;
        int ks = (e >> 9) & 3;
        int ln = (e >> 3) & 63;
        int j  = e & 7;
        int n = nt*16 + (ln & 15);
        int k = ks*32 + (ln >> 4)*8 + j;
        float val = (k < 64)
            ? (att_w1[n*256 + 64 + k] - att_w1[n*256 + 128 + k])
            : att_w1[n*256 + 192 + (k - 64)];
        ((u16*)(ws + WS_WF1F))[e] = f2bf(val);
    } else if (idx < 93776) {
        /* W2cat fragments: S1(200x80,pad96) @ W2cat(96x48): W2cat[k][n]=att_w2[n*80+k] */
        int e  = idx - 89168;
        int nt = e / 1536;
        int ks = (e / 512) % 3;
        int ln = (e >> 3) & 63;
        int j  = e & 7;
        int n = nt*16 + (ln & 15);
        int k = ks*32 + (ln >> 4)*8 + j;
        float val = (n < 40 && k < 80) ? att_w2[n*80 + k] : 0.0f;
        ((u16*)(ws + WS_WF2F))[e] = f2bf(val);
    }
}

__global__ __launch_bounds__(256, 4) void din_kernel(
    const int* __restrict__ uid, const int* __restrict__ gid, const int* __restrict__ cid,
    const int* __restrict__ gid_his, const int* __restrict__ cid_his, const int* __restrict__ masks,
    const float* __restrict__ user_emb, const float* __restrict__ good_emb, const float* __restrict__ cat_emb,
    const float* __restrict__ att_b1, const float* __restrict__ att_b2, const float* __restrict__ att_b3,
    const float* __restrict__ mlp_b1, const float* __restrict__ mlp_b2, const float* __restrict__ mlp_b3,
    const float* __restrict__ pa1, const float* __restrict__ pa2,
    const float* __restrict__ ws, float* __restrict__ out)
{
    /* Xc[200 rows][64 bf16] with 16B-slot XOR swizzle: slot' = slot ^ (row&7)  (25600 B) */
    __shared__ u16 Xc[200*64];
    /* per-wave scratch: [16 rows][104 bf16] (row stride 208 B, 16B-aligned, 52-dword stride -> 2-way banks) */
    __shared__ u16 scr[4*1664];
    __shared__ float q_sh[64];
    __shared__ float c0_sh[80];
    __shared__ float sp_sh[256];
    __shared__ float scal_sh[2];

    /* overlays into scr (only live after the tile loop is done) */
    float* redA  = (float*)scr;       /* 256 */
    float* redU  = redA + 256;        /* 256 */
    float* x_sh  = redU + 256;        /* 288 */
    float* h1_sh = x_sh + 288;        /* 200 */
    float* h2_sh = h1_sh + 200;       /* 80  -> 1080 floats = 4320 B << 13312 B */

    const int b    = blockIdx.x;
    const int tid  = threadIdx.x;
    const int lane = tid & 63;
    const int wv   = tid >> 6;
    const int lrow = lane & 15;
    const int lgrp = lane >> 4;

    /* ---- Phase 0: issue behavior gathers; stage query ---- */
    float4 gbuf[13];
    #pragma unroll
    for (int it = 0; it < 13; ++it) {
        int idx = it*256 + tid;
        if (idx < 3200) {
            int l = idx >> 4, c = idx & 15;
            const float* src = (c < 8)
                ? (good_emb + (size_t)gid_his[b*200 + l]*32 + (c & 7)*4)
                : (cat_emb  + (size_t)cid_his[b*200 + l]*32 + (c & 7)*4);
            gbuf[it] = *(const float4*)src;
        }
    }
    if (tid < 64) {
        q_sh[tid] = (tid < 32) ? good_emb[(size_t)gid[b]*32 + tid]
                               : cat_emb[(size_t)cid[b]*32 + (tid - 32)];
    }
    __syncthreads();

    /* ---- Phase 1: beh -> Xc (bf16, swizzled); c0; sp tail init ---- */
    #pragma unroll
    for (int it = 0; it < 13; ++it) {
        int idx = it*256 + tid;
        if (idx < 3200) {
            int l = idx >> 4, c = idx & 15;
            float4 v = gbuf[it];
            uint2v pk;
            pk[0] = (u32)f2bf(v.x) | ((u32)f2bf(v.y) << 16);
            pk[1] = (u32)f2bf(v.z) | ((u32)f2bf(v.w) << 16);
            int byteoff = l*128 + ((((c >> 1) ^ (l & 7)) << 4)) + ((c & 1) << 3);
            *((uint2v*)((char*)Xc + byteoff)) = pk;
        }
    }
    if (tid < 80) {
        const float* Sw = ws + WS_S + tid*64;
        float u0 = 0.f, u1 = 0.f;
        #pragma unroll
        for (int j = 0; j < 64; j += 2) {
            u0 += q_sh[j]   * Sw[j];
            u1 += q_sh[j+1] * Sw[j+1];
        }
        c0_sh[tid] = att_b1[tid] + u0 + u1;
    }
    if (tid >= 200) sp_sh[tid] = NEG_INF_F;
    __syncthreads();

    /* ---- Phase 2: per-M-tile attention MLP via MFMA ---- */
    f32x8 qf0, qf1;
    #pragma unroll
    for (int j = 0; j < 8; ++j) {
        qf0[j] = q_sh[lgrp*8 + j];
        qf1[j] = q_sh[32 + lgrp*8 + j];
    }
    float c0v[5];
    #pragma unroll
    for (int nt = 0; nt < 5; ++nt) c0v[nt] = c0_sh[nt*16 + lrow];
    float b2v[3];
    #pragma unroll
    for (int nt = 0; nt < 3; ++nt) {
        int col = nt*16 + lrow;
        b2v[nt] = (col < 40) ? att_b2[col] : 0.0f;
    }
    const float bias3 = att_b3[0];

    const short8* WF1 = (const short8*)(ws + WS_WF1F);
    const short8* WF2 = (const short8*)(ws + WS_WF2F);
    u16*   scr_w = scr + wv*1664;
    float* scr_f = (float*)scr_w;

    for (int t = wv; t < 13; t += 4) {
        const int m0 = (t == 12) ? 184 : (t << 4);   /* tile 12 overlaps tile 11: benign same-value race */
        const int m  = m0 + lrow;

        /* A fragments: beh (ks 0,1 from LDS), q*beh (ks 2,3 in-register) */
        short8 A0, A1;
        {
            int sl0 = (0 + lgrp) ^ (m & 7);
            int sl1 = (4 + lgrp) ^ (m & 7);
            A0 = *(const short8*)((const char*)Xc + m*128 + (sl0 << 4));
            A1 = *(const short8*)((const char*)Xc + m*128 + (sl1 << 4));
        }
        short8 A2 = mulqf(A0, qf0);
        short8 A3 = mulqf(A1, qf1);

        /* layer 1: S1(16x80) = sigmoid(Xcat @ W1cat + c0) -> scratch bf16 */
        #pragma unroll
        for (int nt = 0; nt < 5; ++nt) {
            f32x4 acc = {0.f, 0.f, 0.f, 0.f};
            acc = mfma16(A0, WF1[(nt*4 + 0)*64 + lane], acc);
            acc = mfma16(A1, WF1[(nt*4 + 1)*64 + lane], acc);
            acc = mfma16(A2, WF1[(nt*4 + 2)*64 + lane], acc);
            acc = mfma16(A3, WF1[(nt*4 + 3)*64 + lane], acc);
            #pragma unroll
            for (int r = 0; r < 4; ++r) {
                float s1v = fsigmoid(acc[r] + c0v[nt]);
                scr_w[(lgrp*4 + r)*104 + nt*16 + lrow] = f2bf(s1v);
            }
        }
        /* zero-pad S1 cols 80..95 (K pad for layer 2) */
        {
            uint2v z; z[0] = 0u; z[1] = 0u;
            *((uint2v*)(scr_w + lrow*104 + 80 + lgrp*4)) = z;
        }

        /* layer 2: S2(16x48) = sigmoid(S1 @ W2cat + b2) -> scratch f32 */
        short8 B0 = *(const short8*)(scr_w + lrow*104 +  0 + lgrp*8);
        short8 B1 = *(const short8*)(scr_w + lrow*104 + 32 + lgrp*8);
        short8 B2 = *(const short8*)(scr_w + lrow*104 + 64 + lgrp*8);
        #pragma unroll
        for (int nt = 0; nt < 3; ++nt) {
            f32x4 acc = {0.f, 0.f, 0.f, 0.f};
            acc = mfma16(B0, WF2[(nt*3 + 0)*64 + lane], acc);
            acc = mfma16(B1, WF2[(nt*3 + 1)*64 + lane], acc);
            acc = mfma16(B2, WF2[(nt*3 + 2)*64 + lane], acc);
            #pragma unroll
            for (int r = 0; r < 4; ++r) {
                float s2v = fsigmoid(acc[r] + b2v[nt]);
                scr_f[(lgrp*4 + r)*52 + nt*16 + lrow] = s2v;
            }
        }

        /* layer 3: s[row] = b3 + sum_g sigmoid2[row][g]*w3[g]; 4 lanes per row */
        float v3 = 0.f;
        #pragma unroll
        for (int i = 0; i < 10; ++i) {
            int g = lgrp + 4*i;
            v3 += scr_f[lrow*52 + g] * ws[WS_W3P + g];
        }
        v3 += __shfl_xor(v3, 16);
        v3 += __shfl_xor(v3, 32);
        if (lane < 16) {
            int mm = m0 + lane;
            float sval = v3 + bias3;
            int mk = masks[b*200 + mm];
            sp_sh[mm] = mk ? sval : NEG_BIG;
        }
    }
    __syncthreads();

    /* ---- Phase 3: masked softmax over l ---- */
    if (tid < 64) {
        float mv = fmaxf(fmaxf(sp_sh[tid], sp_sh[tid+64]), fmaxf(sp_sh[tid+128], sp_sh[tid+192]));
        #pragma unroll
        for (int off = 32; off > 0; off >>= 1) mv = fmaxf(mv, __shfl_down(mv, off));
        if (tid == 0) scal_sh[0] = mv;
    }
    __syncthreads();
    {
        float mx = scal_sh[0];
        float sm = sp_sh[tid];
        float ev = (tid < 200) ? __expf(sm - mx) : 0.0f;
        sp_sh[tid] = ev;
    }
    __syncthreads();
    if (tid < 64) {
        float s = (sp_sh[tid] + sp_sh[tid+64]) + (sp_sh[tid+128] + sp_sh[tid+192]);
        #pragma unroll
        for (int off = 32; off > 0; off >>= 1) s += __shfl_down(s, off);
        if (tid == 0) scal_sh[1] = s;
    }
    __syncthreads();

    /* ---- Phase 4: pooling att (unnormalized) and ubs from bf16 Xc ---- */
    {
        int j = tid & 63, qq = tid >> 6;
        float accA = 0.f, accU = 0.f;
        int swzbase = (j >> 3);
        int inslot  = (j & 7) << 1;
        #pragma unroll 10
        for (int mm = qq*50; mm < qq*50 + 50; ++mm) {
            int byteoff = mm*128 + (((swzbase ^ (mm & 7)) << 4)) + inslot;
            float bv = bf2f(*(const u16*)((const char*)Xc + byteoff));
            accA += sp_sh[mm] * bv;
            accU += bv;
        }
        redA[tid] = accA;
        redU[tid] = accU;
    }
    __syncthreads();

    float inv = 1.0f / scal_sh[1];
    if (tid < 64) {
        float att = ((redA[tid] + redA[tid+64]) + (redA[tid+128] + redA[tid+192])) * inv;
        float ub  =  (redU[tid] + redU[tid+64]) + (redU[tid+128] + redU[tid+192]);
        x_sh[32  + tid] = q_sh[tid];
        x_sh[96  + tid] = ub;
        x_sh[160 + tid] = ub * q_sh[tid];
        x_sh[224 + tid] = att;
    }
    if (tid >= 64 && tid < 96) {
        x_sh[tid - 64] = user_emb[(size_t)uid[b]*32 + (tid - 64)];
    }
    __syncthreads();

    /* ---- Phase 5: final MLP 288 -> 200 -> 80 -> 2 ---- */
    const float* w1T = ws + WS_W1T;
    if (tid < 200) {
        float A0 = 0.f, A1 = 0.f, A2 = 0.f, A3 = 0.f;
        #pragma unroll 4
        for (int k = 0; k < 288; k += 4) {
            A0 += x_sh[k+0] * w1T[(k+0)*200 + tid];
            A1 += x_sh[k+1] * w1T[(k+1)*200 + tid];
            A2 += x_sh[k+2] * w1T[(k+2)*200 + tid];
            A3 += x_sh[k+3] * w1T[(k+3)*200 + tid];
        }
        float acc = ((A0+A1) + (A2+A3)) + mlp_b1[tid];
        h1_sh[tid] = (acc >= 0.f) ? acc : pa1[tid]*acc;
    }
    __syncthreads();
    const float* w2T = ws + WS_W2T;
    if (tid < 80) {
        float A0 = 0.f, A1 = 0.f, A2 = 0.f, A3 = 0.f;
        #pragma unroll 4
        for (int k = 0; k < 200; k += 4) {
            A0 += h1_sh[k+0] * w2T[(k+0)*80 + tid];
            A1 += h1_sh[k+1] * w2T[(k+1)*80 + tid];
            A2 += h1_sh[k+2] * w2T[(k+2)*80 + tid];
            A3 += h1_sh[k+3] * w2T[(k+3)*80 + tid];
        }
        float acc = ((A0+A1) + (A2+A3)) + mlp_b2[tid];
        h2_sh[tid] = (acc >= 0.f) ? acc : pa2[tid]*acc;
    }
    __syncthreads();
    if (tid < 2) {
        const float* w3T = ws + WS_W3T;
        float acc = mlp_b3[tid];
        #pragma unroll 8
        for (int k = 0; k < 80; ++k) acc += h2_sh[k] * w3T[k*2 + tid];
        out[b*2 + tid] = acc;
    }
}

extern "C" void kernel_launch(void* const* d_in, const int* in_sizes, int n_in,
                              void* d_out, int out_size, void* d_ws, size_t ws_size,
                              hipStream_t stream) {
    const int*   uid      = (const int*)d_in[0];
    const int*   gid      = (const int*)d_in[1];
    const int*   cid      = (const int*)d_in[2];
    const int*   gid_his  = (const int*)d_in[3];
    const int*   cid_his  = (const int*)d_in[4];
    const int*   masks    = (const int*)d_in[5];
    const float* user_emb = (const float*)d_in[6];
    const float* good_emb = (const float*)d_in[7];
    const float* cat_emb  = (const float*)d_in[8];
    const float* att_w1   = (const float*)d_in[9];
    const float* att_b1   = (const float*)d_in[10];
    const float* att_w2   = (const float*)d_in[11];
    const float* att_b2   = (const float*)d_in[12];
    const float* att_w3   = (const float*)d_in[13];
    const float* att_b3   = (const float*)d_in[14];
    const float* mlp_w1   = (const float*)d_in[15];
    const float* mlp_b1   = (const float*)d_in[16];
    const float* mlp_w2   = (const float*)d_in[17];
    const float* mlp_b2   = (const float*)d_in[18];
    const float* mlp_w3   = (const float*)d_in[19];
    const float* mlp_b3   = (const float*)d_in[20];
    const float* pa1      = (const float*)d_in[21];
    const float* pa2      = (const float*)d_in[22];
    float* ws   = (float*)d_ws;
    float* outp = (float*)d_out;

    hipLaunchKernelGGL(prep_kernel, dim3(367), dim3(256), 0, stream,
                       att_w1, att_w2, att_w3, mlp_w1, mlp_w2, mlp_w3, ws);
    hipLaunchKernelGGL(din_kernel, dim3(4096), dim3(256), 0, stream,
                       uid, gid, cid, gid_his, cid_his, masks,
                       user_emb, good_emb, cat_emb,
                       att_b1, att_b2, att_b3,
                       mlp_b1, mlp_b2, mlp_b3, pa1, pa2, ws, outp);
}

// Round 3
// 301.669 us; speedup vs baseline: 3.3309x; 1.0198x over previous
//
#include <hip/hip_runtime.h>
#include <math.h>

typedef unsigned short u16;
typedef unsigned int u32;
typedef __attribute__((ext_vector_type(8))) short short8;
typedef __attribute__((ext_vector_type(8))) float f32x8;
typedef __attribute__((ext_vector_type(4))) float f32x4;
typedef __attribute__((ext_vector_type(2))) unsigned int uint2v;

#define NEG_BIG   (-4294967296.0f)   /* float32(-2^32+1) */
#define NEG_INF_F (-__builtin_inff())

/* ---- workspace layout (float offsets) ---- */
#define WS_S    0        /* [80][64] f32: w1[:,0:64]+w1[:,128:192] (for c0) */
#define WS_W1T  5120     /* [288][200] f32 mlp_w1^T */
#define WS_W2T  62720    /* [200][80]  f32 mlp_w2^T */
#define WS_W3T  78720    /* [80][2]    f32 mlp_w3^T */
#define WS_W3P  78880    /* [48] f32 att_w3 zero-padded */
#define WS_WF1F 78928    /* 10240 bf16 = 5120 float-slots: W1cat frags [5 nt][4 ks][64 lane][8] */
#define WS_WF2F 84048    /* 4608 bf16 = 2304 float-slots: W2cat frags [3 nt][3 ks][64 lane][8] */
/* total 86352 floats = 345.4 KB */

__device__ __forceinline__ u16 f2bf(float f) {
    union { float f; u32 u; } v; v.f = f;
    u32 r = v.u + 0x7FFFu + ((v.u >> 16) & 1u);
    return (u16)(r >> 16);
}
__device__ __forceinline__ float bf2f(u16 h) {
    union { u32 u; float f; } v; v.u = ((u32)h) << 16;
    return v.f;
}
__device__ __forceinline__ float fsigmoid(float x) {
    return __fdividef(1.0f, 1.0f + __expf(-x));
}
__device__ __forceinline__ short8 mulqf(short8 a, f32x8 qf) {
    short8 r;
    #pragma unroll
    for (int j = 0; j < 8; ++j) r[j] = (short)f2bf(bf2f((u16)a[j]) * qf[j]);
    return r;
}
__device__ __forceinline__ f32x4 mfma16(short8 a, short8 b, f32x4 c) {
    return __builtin_amdgcn_mfma_f32_16x16x32_bf16(a, b, c, 0, 0, 0);
}

__global__ __launch_bounds__(256) void prep_kernel(
    const float* __restrict__ att_w1,
    const float* __restrict__ att_w2,
    const float* __restrict__ att_w3,
    const float* __restrict__ mlp_w1,
    const float* __restrict__ mlp_w2,
    const float* __restrict__ mlp_w3,
    float* __restrict__ ws)
{
    int idx = blockIdx.x * 256 + threadIdx.x;
    if (idx < 5120) {
        int h = idx >> 6, j = idx & 63;
        ws[WS_S + idx] = att_w1[h*256 + j] + att_w1[h*256 + 128 + j];
    } else if (idx < 62720) {
        int r = idx - 5120;            /* r = k*200 + t */
        int k = r / 200, t = r - k*200;
        ws[WS_W1T + r] = mlp_w1[t*288 + k];
    } else if (idx < 78720) {
        int r = idx - 62720;           /* r = k*80 + g */
        int k = r / 80, g = r - k*80;
        ws[WS_W2T + r] = mlp_w2[g*200 + k];
    } else if (idx < 78880) {
        int r = idx - 78720;           /* r = k*2 + o */
        int k = r >> 1, o = r & 1;
        ws[WS_W3T + r] = mlp_w3[o*80 + k];
    } else if (idx < 78928) {
        int g = idx - 78880;
        ws[WS_W3P + g] = (g < 40) ? att_w3[g] : 0.0f;
    } else if (idx < 89168) {
        /* W1cat fragments: Xcat(200x128) @ W1cat(128x80)
           k<64: beh rows -> w1[:,64:128]-w1[:,128:192]; k>=64: q*beh -> w1[:,192:256] */
        int e  = idx - 78928;
        int nt = e >> 11;
        int ks = (e >> 9) & 3;
        int ln = (e >> 3) & 63;
        int j  = e & 7;
        int n = nt*16 + (ln & 15);
        int k = ks*32 + (ln >> 4)*8 + j;
        float val = (k < 64)
            ? (att_w1[n*256 + 64 + k] - att_w1[n*256 + 128 + k])
            : att_w1[n*256 + 192 + (k - 64)];
        ((u16*)(ws + WS_WF1F))[e] = f2bf(val);
    } else if (idx < 93776) {
        /* W2cat fragments: S1(200x80,pad96) @ W2cat(96x48): W2cat[k][n]=att_w2[n*80+k] */
        int e  = idx - 89168;
        int nt = e / 1536;
        int ks = (e / 512) % 3;
        int ln = (e >> 3) & 63;
        int j  = e & 7;
        int n = nt*16 + (ln & 15);
        int k = ks*32 + (ln >> 4)*8 + j;
        float val = (n < 40 && k < 80) ? att_w2[n*80 + k] : 0.0f;
        ((u16*)(ws + WS_WF2F))[e] = f2bf(val);
    }
}

__global__ __launch_bounds__(256, 4) void din_kernel(
    const int* __restrict__ uid, const int* __restrict__ gid, const int* __restrict__ cid,
    const int* __restrict__ gid_his, const int* __restrict__ cid_his, const int* __restrict__ masks,
    const float* __restrict__ user_emb, const float* __restrict__ good_emb, const float* __restrict__ cat_emb,
    const float* __restrict__ att_b1, const float* __restrict__ att_b2, const float* __restrict__ att_b3,
    const float* __restrict__ mlp_b1, const float* __restrict__ mlp_b2, const float* __restrict__ mlp_b3,
    const float* __restrict__ pa1, const float* __restrict__ pa2,
    const float* __restrict__ ws, float* __restrict__ out)
{
    /* Xc[200 rows][64 bf16] with 16B-slot XOR swizzle: slot' = slot ^ (row&7)  (25600 B) */
    __shared__ u16 Xc[200*64];
    /* per-wave scratch: [16 rows][104 bf16] (row stride 208 B, 16B-aligned) */
    __shared__ u16 scr[4*1664];
    __shared__ float q_sh[64];
    __shared__ float c0_sh[80];
    __shared__ float sp_sh[256];
    __shared__ float scal_sh[2];

    /* overlays into scr (only live after the tile loop is done) */
    float* redA  = (float*)scr;       /* 256 */
    float* redU  = redA + 256;        /* 256 */
    float* x_sh  = redU + 256;        /* 288 */
    float* h1_sh = x_sh + 288;        /* 200 */
    float* h2_sh = h1_sh + 200;       /* 80 */

    const int b    = blockIdx.x;
    const int tid  = threadIdx.x;
    const int lane = tid & 63;
    const int wv   = tid >> 6;
    const int lrow = lane & 15;
    const int lgrp = lane >> 4;

    const int* gh = gid_his + b*200;
    const int* ch = cid_his + b*200;

    /* ---- Phase 0/1 fused: gather -> bf16 -> Xc (swizzled), no register staging ---- */
    #pragma unroll
    for (int it = 0; it < 12; ++it) {
        int idx = it*256 + tid;
        int l = idx >> 4, c = idx & 15;
        const float* src = (c < 8)
            ? (good_emb + (size_t)gh[l]*32 + (c & 7)*4)
            : (cat_emb  + (size_t)ch[l]*32 + (c & 7)*4);
        float4 v = *(const float4*)src;
        uint2v pk;
        pk[0] = (u32)f2bf(v.x) | ((u32)f2bf(v.y) << 16);
        pk[1] = (u32)f2bf(v.z) | ((u32)f2bf(v.w) << 16);
        int byteoff = l*128 + ((((c >> 1) ^ (l & 7)) << 4)) + ((c & 1) << 3);
        *((uint2v*)((char*)Xc + byteoff)) = pk;
    }
    if (tid < 128) {
        int idx = 3072 + tid;
        int l = idx >> 4, c = idx & 15;
        const float* src = (c < 8)
            ? (good_emb + (size_t)gh[l]*32 + (c & 7)*4)
            : (cat_emb  + (size_t)ch[l]*32 + (c & 7)*4);
        float4 v = *(const float4*)src;
        uint2v pk;
        pk[0] = (u32)f2bf(v.x) | ((u32)f2bf(v.y) << 16);
        pk[1] = (u32)f2bf(v.z) | ((u32)f2bf(v.w) << 16);
        int byteoff = l*128 + ((((c >> 1) ^ (l & 7)) << 4)) + ((c & 1) << 3);
        *((uint2v*)((char*)Xc + byteoff)) = pk;
    }
    if (tid < 64) {
        q_sh[tid] = (tid < 32) ? good_emb[(size_t)gid[b]*32 + tid]
                               : cat_emb[(size_t)cid[b]*32 + (tid - 32)];
    }
    if (tid >= 200 && tid < 256) sp_sh[tid] = NEG_INF_F;
    __syncthreads();

    /* c0[h] = b1[h] + sum_j q_j*(W1[h,j]+W1[h,128+j]) */
    if (tid < 80) {
        const float* Sw = ws + WS_S + tid*64;
        float u0 = 0.f, u1 = 0.f;
        #pragma unroll
        for (int j = 0; j < 64; j += 2) {
            u0 += q_sh[j]   * Sw[j];
            u1 += q_sh[j+1] * Sw[j+1];
        }
        c0_sh[tid] = att_b1[tid] + u0 + u1;
    }
    __syncthreads();

    /* ---- Phase 2: per-M-tile attention MLP via MFMA ---- */
    f32x8 qf0, qf1;
    #pragma unroll
    for (int j = 0; j < 8; ++j) {
        qf0[j] = q_sh[lgrp*8 + j];
        qf1[j] = q_sh[32 + lgrp*8 + j];
    }
    float c0v[5];
    #pragma unroll
    for (int nt = 0; nt < 5; ++nt) c0v[nt] = c0_sh[nt*16 + lrow];
    float b2v[3];
    #pragma unroll
    for (int nt = 0; nt < 3; ++nt) {
        int col = nt*16 + lrow;
        b2v[nt] = (col < 40) ? att_b2[col] : 0.0f;
    }
    const float bias3 = att_b3[0];

    const short8* WF1 = (const short8*)(ws + WS_WF1F);
    const short8* WF2 = (const short8*)(ws + WS_WF2F);
    u16*   scr_w = scr + wv*1664;
    float* scr_f = (float*)scr_w;

    for (int t = wv; t < 13; t += 4) {
        const int m0 = (t == 12) ? 184 : (t << 4);   /* tile 12 overlaps tile 11: benign same-value race */
        const int m  = m0 + lrow;

        /* A fragments: beh (ks 0,1 from LDS), q*beh (ks 2,3 in-register) */
        short8 A0, A1;
        {
            int sl0 = (0 + lgrp) ^ (m & 7);
            int sl1 = (4 + lgrp) ^ (m & 7);
            A0 = *(const short8*)((const char*)Xc + m*128 + (sl0 << 4));
            A1 = *(const short8*)((const char*)Xc + m*128 + (sl1 << 4));
        }
        short8 A2 = mulqf(A0, qf0);
        short8 A3 = mulqf(A1, qf1);

        /* layer 1: S1(16x80) = sigmoid(Xcat @ W1cat + c0) -> scratch bf16 */
        #pragma unroll
        for (int nt = 0; nt < 5; ++nt) {
            f32x4 acc = {0.f, 0.f, 0.f, 0.f};
            acc = mfma16(A0, WF1[(nt*4 + 0)*64 + lane], acc);
            acc = mfma16(A1, WF1[(nt*4 + 1)*64 + lane], acc);
            acc = mfma16(A2, WF1[(nt*4 + 2)*64 + lane], acc);
            acc = mfma16(A3, WF1[(nt*4 + 3)*64 + lane], acc);
            #pragma unroll
            for (int r = 0; r < 4; ++r) {
                float s1v = fsigmoid(acc[r] + c0v[nt]);
                scr_w[(lgrp*4 + r)*104 + nt*16 + lrow] = f2bf(s1v);
            }
        }
        /* zero-pad S1 cols 80..95 (K pad for layer 2) */
        {
            uint2v z; z[0] = 0u; z[1] = 0u;
            *((uint2v*)(scr_w + lrow*104 + 80 + lgrp*4)) = z;
        }

        /* layer 2: S2(16x48) = sigmoid(S1 @ W2cat + b2) -> scratch f32 */
        short8 B0 = *(const short8*)(scr_w + lrow*104 +  0 + lgrp*8);
        short8 B1 = *(const short8*)(scr_w + lrow*104 + 32 + lgrp*8);
        short8 B2 = *(const short8*)(scr_w + lrow*104 + 64 + lgrp*8);
        #pragma unroll
        for (int nt = 0; nt < 3; ++nt) {
            f32x4 acc = {0.f, 0.f, 0.f, 0.f};
            acc = mfma16(B0, WF2[(nt*3 + 0)*64 + lane], acc);
            acc = mfma16(B1, WF2[(nt*3 + 1)*64 + lane], acc);
            acc = mfma16(B2, WF2[(nt*3 + 2)*64 + lane], acc);
            #pragma unroll
            for (int r = 0; r < 4; ++r) {
                float s2v = fsigmoid(acc[r] + b2v[nt]);
                scr_f[(lgrp*4 + r)*52 + nt*16 + lrow] = s2v;
            }
        }

        /* layer 3: s[row] = b3 + sum_g sigmoid2[row][g]*w3[g]; 4 lanes per row */
        float v3 = 0.f;
        #pragma unroll
        for (int i = 0; i < 10; ++i) {
            int g = lgrp + 4*i;
            v3 += scr_f[lrow*52 + g] * ws[WS_W3P + g];
        }
        v3 += __shfl_xor(v3, 16);
        v3 += __shfl_xor(v3, 32);
        if (lane < 16) {
            int mm = m0 + lane;
            float sval = v3 + bias3;
            int mk = masks[b*200 + mm];
            sp_sh[mm] = mk ? sval : NEG_BIG;
        }
    }
    __syncthreads();

    /* ---- Phase 3: masked softmax over l ---- */
    if (tid < 64) {
        float mv = fmaxf(fmaxf(sp_sh[tid], sp_sh[tid+64]), fmaxf(sp_sh[tid+128], sp_sh[tid+192]));
        #pragma unroll
        for (int off = 32; off > 0; off >>= 1) mv = fmaxf(mv, __shfl_down(mv, off));
        if (tid == 0) scal_sh[0] = mv;
    }
    __syncthreads();
    {
        float mx = scal_sh[0];
        float sm = sp_sh[tid];
        float ev = (tid < 200) ? __expf(sm - mx) : 0.0f;
        sp_sh[tid] = ev;
    }
    __syncthreads();
    if (tid < 64) {
        float s = (sp_sh[tid] + sp_sh[tid+64]) + (sp_sh[tid+128] + sp_sh[tid+192]);
        #pragma unroll
        for (int off = 32; off > 0; off >>= 1) s += __shfl_down(s, off);
        if (tid == 0) scal_sh[1] = s;
    }
    __syncthreads();

    /* ---- Phase 4: pooling att (unnormalized) and ubs from bf16 Xc ---- */
    {
        int j = tid & 63, qq = tid >> 6;
        float accA = 0.f, accU = 0.f;
        int swzbase = (j >> 3);
        int inslot  = (j & 7) << 1;
        #pragma unroll 10
        for (int mm = qq*50; mm < qq*50 + 50; ++mm) {
            int byteoff = mm*128 + (((swzbase ^ (mm & 7)) << 4)) + inslot;
            float bv = bf2f(*(const u16*)((const char*)Xc + byteoff));
            accA += sp_sh[mm] * bv;
            accU += bv;
        }
        redA[tid] = accA;
        redU[tid] = accU;
    }
    __syncthreads();

    float inv = 1.0f / scal_sh[1];
    if (tid < 64) {
        float att = ((redA[tid] + redA[tid+64]) + (redA[tid+128] + redA[tid+192])) * inv;
        float ub  =  (redU[tid] + redU[tid+64]) + (redU[tid+128] + redU[tid+192]);
        x_sh[32  + tid] = q_sh[tid];
        x_sh[96  + tid] = ub;
        x_sh[160 + tid] = ub * q_sh[tid];
        x_sh[224 + tid] = att;
    }
    if (tid >= 64 && tid < 96) {
        x_sh[tid - 64] = user_emb[(size_t)uid[b]*32 + (tid - 64)];
    }
    __syncthreads();

    /* ---- Phase 5: final MLP 288 -> 200 -> 80 -> 2 ---- */
    const float* w1T = ws + WS_W1T;
    if (tid < 200) {
        float A0 = 0.f, A1 = 0.f, A2 = 0.f, A3 = 0.f;
        #pragma unroll 4
        for (int k = 0; k < 288; k += 4) {
            A0 += x_sh[k+0] * w1T[(k+0)*200 + tid];
            A1 += x_sh[k+1] * w1T[(k+1)*200 + tid];
            A2 += x_sh[k+2] * w1T[(k+2)*200 + tid];
            A3 += x_sh[k+3] * w1T[(k+3)*200 + tid];
        }
        float acc = ((A0+A1) + (A2+A3)) + mlp_b1[tid];
        h1_sh[tid] = (acc >= 0.f) ? acc : pa1[tid]*acc;
    }
    __syncthreads();
    const float* w2T = ws + WS_W2T;
    if (tid < 80) {
        float A0 = 0.f, A1 = 0.f, A2 = 0.f, A3 = 0.f;
        #pragma unroll 4
        for (int k = 0; k < 200; k += 4) {
            A0 += h1_sh[k+0] * w2T[(k+0)*80 + tid];
            A1 += h1_sh[k+1] * w2T[(k+1)*80 + tid];
            A2 += h1_sh[k+2] * w2T[(k+2)*80 + tid];
            A3 += h1_sh[k+3] * w2T[(k+3)*80 + tid];
        }
        float acc = ((A0+A1) + (A2+A3)) + mlp_b2[tid];
        h2_sh[tid] = (acc >= 0.f) ? acc : pa2[tid]*acc;
    }
    __syncthreads();
    if (tid < 2) {
        const float* w3T = ws + WS_W3T;
        float acc = mlp_b3[tid];
        #pragma unroll 8
        for (int k = 0; k < 80; ++k) acc += h2_sh[k] * w3T[k*2 + tid];
        out[b*2 + tid] = acc;
    }
}

extern "C" void kernel_launch(void* const* d_in, const int* in_sizes, int n_in,
                              void* d_out, int out_size, void* d_ws, size_t ws_size,
                              hipStream_t stream) {
    const int*   uid      = (const int*)d_in[0];
    const int*   gid      = (const int*)d_in[1];
    const int*   cid      = (const int*)d_in[2];
    const int*   gid_his  = (const int*)d_in[3];
    const int*   cid_his  = (const int*)d_in[4];
    const int*   masks    = (const int*)d_in[5];
    const float* user_emb = (const float*)d_in[6];
    const float* good_emb = (const float*)d_in[7];
    const float* cat_emb  = (const float*)d_in[8];
    const float* att_w1   = (const float*)d_in[9];
    const float* att_b1   = (const float*)d_in[10];
    const float* att_w2   = (const float*)d_in[11];
    const float* att_b2   = (const float*)d_in[12];
    const float* att_w3   = (const float*)d_in[13];
    const float* att_b3   = (const float*)d_in[14];
    const float* mlp_w1   = (const float*)d_in[15];
    const float* mlp_b1   = (const float*)d_in[16];
    const float* mlp_w2   = (const float*)d_in[17];
    const float* mlp_b2   = (const float*)d_in[18];
    const float* mlp_w3   = (const float*)d_in[19];
    const float* mlp_b3   = (const float*)d_in[20];
    const float* pa1      = (const float*)d_in[21];
    const float* pa2      = (const float*)d_in[22];
    float* ws   = (float*)d_ws;
    float* outp = (float*)d_out;

    hipLaunchKernelGGL(prep_kernel, dim3(367), dim3(256), 0, stream,
                       att_w1, att_w2, att_w3, mlp_w1, mlp_w2, mlp_w3, ws);
    hipLaunchKernelGGL(din_kernel, dim3(4096), dim3(256), 0, stream,
                       uid, gid, cid, gid_his, cid_his, masks,
                       user_emb, good_emb, cat_emb,
                       att_b1, att_b2, att_b3,
                       mlp_b1, mlp_b2, mlp_b3, pa1, pa2, ws, outp);
}

// Round 4
// 283.523 us; speedup vs baseline: 3.5441x; 1.0640x over previous
//
#include <hip/hip_runtime.h>
#include <math.h>

typedef unsigned short u16;
typedef unsigned int u32;
typedef __attribute__((ext_vector_type(8))) short short8;
typedef __attribute__((ext_vector_type(8))) float f32x8;
typedef __attribute__((ext_vector_type(4))) float f32x4;
typedef __attribute__((ext_vector_type(2))) unsigned int uint2v;

#define NEG_BIG   (-4294967296.0f)   /* float32(-2^32+1) */
#define NEG_INF_F (-__builtin_inff())

/* ---- workspace layout (float offsets) ---- */
#define WS_S    0        /* [80][64] f32: w1[:,0:64]+w1[:,128:192] (for c0) */
#define WS_W1T  5120     /* [288][200] f32 mlp_w1^T */
#define WS_W2T  62720    /* [200][80]  f32 mlp_w2^T */
#define WS_W3T  78720    /* [80][2]    f32 mlp_w3^T */
#define WS_W3P  78880    /* [48] f32 att_w3 zero-padded */
#define WS_WF1F 78928    /* 10240 bf16 = 5120 float-slots: W1cat frags [5 nt][4 ks][64 lane][8] */
#define WS_WF2F 84048    /* 4608 bf16 = 2304 float-slots: W2cat frags [3 nt][3 ks][64 lane][8] */
#define WS_XF   86352    /* [4096][288] f32 feature rows (kernel A -> kernel B) */
/* total 86352 + 1179648 floats ~= 5.1 MB */

__device__ __forceinline__ u16 f2bf(float f) {
    union { float f; u32 u; } v; v.f = f;
    u32 r = v.u + 0x7FFFu + ((v.u >> 16) & 1u);
    return (u16)(r >> 16);
}
__device__ __forceinline__ float bf2f(u16 h) {
    union { u32 u; float f; } v; v.u = ((u32)h) << 16;
    return v.f;
}
__device__ __forceinline__ float fsigmoid(float x) {
    return __fdividef(1.0f, 1.0f + __expf(-x));
}
__device__ __forceinline__ short8 mulqf(short8 a, f32x8 qf) {
    short8 r;
    #pragma unroll
    for (int j = 0; j < 8; ++j) r[j] = (short)f2bf(bf2f((u16)a[j]) * qf[j]);
    return r;
}
__device__ __forceinline__ f32x4 mfma16(short8 a, short8 b, f32x4 c) {
    return __builtin_amdgcn_mfma_f32_16x16x32_bf16(a, b, c, 0, 0, 0);
}

__global__ __launch_bounds__(256) void prep_kernel(
    const float* __restrict__ att_w1,
    const float* __restrict__ att_w2,
    const float* __restrict__ att_w3,
    const float* __restrict__ mlp_w1,
    const float* __restrict__ mlp_w2,
    const float* __restrict__ mlp_w3,
    float* __restrict__ ws)
{
    int idx = blockIdx.x * 256 + threadIdx.x;
    if (idx < 5120) {
        int h = idx >> 6, j = idx & 63;
        ws[WS_S + idx] = att_w1[h*256 + j] + att_w1[h*256 + 128 + j];
    } else if (idx < 62720) {
        int r = idx - 5120;            /* r = k*200 + t */
        int k = r / 200, t = r - k*200;
        ws[WS_W1T + r] = mlp_w1[t*288 + k];
    } else if (idx < 78720) {
        int r = idx - 62720;           /* r = k*80 + g */
        int k = r / 80, g = r - k*80;
        ws[WS_W2T + r] = mlp_w2[g*200 + k];
    } else if (idx < 78880) {
        int r = idx - 78720;           /* r = k*2 + o */
        int k = r >> 1, o = r & 1;
        ws[WS_W3T + r] = mlp_w3[o*80 + k];
    } else if (idx < 78928) {
        int g = idx - 78880;
        ws[WS_W3P + g] = (g < 40) ? att_w3[g] : 0.0f;
    } else if (idx < 89168) {
        /* W1cat fragments: Xcat(200x128) @ W1cat(128x80)
           k<64: beh rows -> w1[:,64:128]-w1[:,128:192]; k>=64: q*beh -> w1[:,192:256] */
        int e  = idx - 78928;
        int nt = e >> 11;
        int ks = (e >> 9) & 3;
        int ln = (e >> 3) & 63;
        int j  = e & 7;
        int n = nt*16 + (ln & 15);
        int k = ks*32 + (ln >> 4)*8 + j;
        float val = (k < 64)
            ? (att_w1[n*256 + 64 + k] - att_w1[n*256 + 128 + k])
            : att_w1[n*256 + 192 + (k - 64)];
        ((u16*)(ws + WS_WF1F))[e] = f2bf(val);
    } else if (idx < 93776) {
        /* W2cat fragments: S1(200x80,pad96) @ W2cat(96x48): W2cat[k][n]=att_w2[n*80+k] */
        int e  = idx - 89168;
        int nt = e / 1536;
        int ks = (e / 512) % 3;
        int ln = (e >> 3) & 63;
        int j  = e & 7;
        int n = nt*16 + (ln & 15);
        int k = ks*32 + (ln >> 4)*8 + j;
        float val = (n < 40 && k < 80) ? att_w2[n*80 + k] : 0.0f;
        ((u16*)(ws + WS_WF2F))[e] = f2bf(val);
    }
}

/* ---- Kernel A: gather + attention + softmax + pooling -> feature row X[b][288] ---- */
__global__ __launch_bounds__(256, 4) void din_kernel(
    const int* __restrict__ uid, const int* __restrict__ gid, const int* __restrict__ cid,
    const int* __restrict__ gid_his, const int* __restrict__ cid_his, const int* __restrict__ masks,
    const float* __restrict__ user_emb, const float* __restrict__ good_emb, const float* __restrict__ cat_emb,
    const float* __restrict__ att_b1, const float* __restrict__ att_b2, const float* __restrict__ att_b3,
    const float* __restrict__ ws, float* __restrict__ Xg)
{
    /* Xc[200 rows][64 bf16] with 16B-slot XOR swizzle: slot' = slot ^ (row&7)  (25600 B) */
    __shared__ u16 Xc[200*64];
    /* per-wave scratch: [16 rows][104 bf16] (row stride 208 B, 16B-aligned) */
    __shared__ u16 scr[4*1664];
    __shared__ float q_sh[64];
    __shared__ float c0_sh[80];
    __shared__ float sp_sh[256];
    __shared__ float scal_sh[2];

    /* overlays into scr (only live after the tile loop is done) */
    float* redA  = (float*)scr;       /* 256 */
    float* redU  = redA + 256;        /* 256 */

    const int b    = blockIdx.x;
    const int tid  = threadIdx.x;
    const int lane = tid & 63;
    const int wv   = tid >> 6;
    const int lrow = lane & 15;
    const int lgrp = lane >> 4;

    const int* gh = gid_his + b*200;
    const int* ch = cid_his + b*200;

    /* ---- Phase 0/1 fused: gather -> bf16 -> Xc (swizzled) ---- */
    #pragma unroll
    for (int it = 0; it < 12; ++it) {
        int idx = it*256 + tid;
        int l = idx >> 4, c = idx & 15;
        const float* src = (c < 8)
            ? (good_emb + (size_t)gh[l]*32 + (c & 7)*4)
            : (cat_emb  + (size_t)ch[l]*32 + (c & 7)*4);
        float4 v = *(const float4*)src;
        uint2v pk;
        pk[0] = (u32)f2bf(v.x) | ((u32)f2bf(v.y) << 16);
        pk[1] = (u32)f2bf(v.z) | ((u32)f2bf(v.w) << 16);
        int byteoff = l*128 + ((((c >> 1) ^ (l & 7)) << 4)) + ((c & 1) << 3);
        *((uint2v*)((char*)Xc + byteoff)) = pk;
    }
    if (tid < 128) {
        int idx = 3072 + tid;
        int l = idx >> 4, c = idx & 15;
        const float* src = (c < 8)
            ? (good_emb + (size_t)gh[l]*32 + (c & 7)*4)
            : (cat_emb  + (size_t)ch[l]*32 + (c & 7)*4);
        float4 v = *(const float4*)src;
        uint2v pk;
        pk[0] = (u32)f2bf(v.x) | ((u32)f2bf(v.y) << 16);
        pk[1] = (u32)f2bf(v.z) | ((u32)f2bf(v.w) << 16);
        int byteoff = l*128 + ((((c >> 1) ^ (l & 7)) << 4)) + ((c & 1) << 3);
        *((uint2v*)((char*)Xc + byteoff)) = pk;
    }
    if (tid < 64) {
        q_sh[tid] = (tid < 32) ? good_emb[(size_t)gid[b]*32 + tid]
                               : cat_emb[(size_t)cid[b]*32 + (tid - 32)];
    }
    if (tid >= 200 && tid < 256) sp_sh[tid] = NEG_INF_F;
    __syncthreads();

    /* c0[h] = b1[h] + sum_j q_j*(W1[h,j]+W1[h,128+j]) */
    if (tid < 80) {
        const float* Sw = ws + WS_S + tid*64;
        float u0 = 0.f, u1 = 0.f;
        #pragma unroll
        for (int j = 0; j < 64; j += 2) {
            u0 += q_sh[j]   * Sw[j];
            u1 += q_sh[j+1] * Sw[j+1];
        }
        c0_sh[tid] = att_b1[tid] + u0 + u1;
    }
    __syncthreads();

    /* ---- Phase 2: per-M-tile attention MLP via MFMA ---- */
    f32x8 qf0, qf1;
    #pragma unroll
    for (int j = 0; j < 8; ++j) {
        qf0[j] = q_sh[lgrp*8 + j];
        qf1[j] = q_sh[32 + lgrp*8 + j];
    }
    float c0v[5];
    #pragma unroll
    for (int nt = 0; nt < 5; ++nt) c0v[nt] = c0_sh[nt*16 + lrow];
    float b2v[3];
    #pragma unroll
    for (int nt = 0; nt < 3; ++nt) {
        int col = nt*16 + lrow;
        b2v[nt] = (col < 40) ? att_b2[col] : 0.0f;
    }
    const float bias3 = att_b3[0];

    const short8* WF1 = (const short8*)(ws + WS_WF1F);
    const short8* WF2 = (const short8*)(ws + WS_WF2F);
    u16*   scr_w = scr + wv*1664;
    float* scr_f = (float*)scr_w;

    for (int t = wv; t < 13; t += 4) {
        const int m0 = (t == 12) ? 184 : (t << 4);   /* tile 12 overlaps tile 11: benign same-value race */
        const int m  = m0 + lrow;

        /* A fragments: beh (ks 0,1 from LDS), q*beh (ks 2,3 in-register) */
        short8 A0, A1;
        {
            int sl0 = (0 + lgrp) ^ (m & 7);
            int sl1 = (4 + lgrp) ^ (m & 7);
            A0 = *(const short8*)((const char*)Xc + m*128 + (sl0 << 4));
            A1 = *(const short8*)((const char*)Xc + m*128 + (sl1 << 4));
        }
        short8 A2 = mulqf(A0, qf0);
        short8 A3 = mulqf(A1, qf1);

        /* layer 1: S1(16x80) = sigmoid(Xcat @ W1cat + c0) -> scratch bf16 */
        #pragma unroll
        for (int nt = 0; nt < 5; ++nt) {
            f32x4 acc = {0.f, 0.f, 0.f, 0.f};
            acc = mfma16(A0, WF1[(nt*4 + 0)*64 + lane], acc);
            acc = mfma16(A1, WF1[(nt*4 + 1)*64 + lane], acc);
            acc = mfma16(A2, WF1[(nt*4 + 2)*64 + lane], acc);
            acc = mfma16(A3, WF1[(nt*4 + 3)*64 + lane], acc);
            #pragma unroll
            for (int r = 0; r < 4; ++r) {
                float s1v = fsigmoid(acc[r] + c0v[nt]);
                scr_w[(lgrp*4 + r)*104 + nt*16 + lrow] = f2bf(s1v);
            }
        }
        /* zero-pad S1 cols 80..95 (K pad for layer 2) */
        {
            uint2v z; z[0] = 0u; z[1] = 0u;
            *((uint2v*)(scr_w + lrow*104 + 80 + lgrp*4)) = z;
        }

        /* layer 2: S2(16x48) = sigmoid(S1 @ W2cat + b2) -> scratch f32 */
        short8 B0 = *(const short8*)(scr_w + lrow*104 +  0 + lgrp*8);
        short8 B1 = *(const short8*)(scr_w + lrow*104 + 32 + lgrp*8);
        short8 B2 = *(const short8*)(scr_w + lrow*104 + 64 + lgrp*8);
        #pragma unroll
        for (int nt = 0; nt < 3; ++nt) {
            f32x4 acc = {0.f, 0.f, 0.f, 0.f};
            acc = mfma16(B0, WF2[(nt*3 + 0)*64 + lane], acc);
            acc = mfma16(B1, WF2[(nt*3 + 1)*64 + lane], acc);
            acc = mfma16(B2, WF2[(nt*3 + 2)*64 + lane], acc);
            #pragma unroll
            for (int r = 0; r < 4; ++r) {
                float s2v = fsigmoid(acc[r] + b2v[nt]);
                scr_f[(lgrp*4 + r)*52 + nt*16 + lrow] = s2v;
            }
        }

        /* layer 3: s[row] = b3 + sum_g sigmoid2[row][g]*w3[g]; 4 lanes per row */
        float v3 = 0.f;
        #pragma unroll
        for (int i = 0; i < 10; ++i) {
            int g = lgrp + 4*i;
            v3 += scr_f[lrow*52 + g] * ws[WS_W3P + g];
        }
        v3 += __shfl_xor(v3, 16);
        v3 += __shfl_xor(v3, 32);
        if (lane < 16) {
            int mm = m0 + lane;
            float sval = v3 + bias3;
            int mk = masks[b*200 + mm];
            sp_sh[mm] = mk ? sval : NEG_BIG;
        }
    }
    __syncthreads();

    /* ---- Phase 3: masked softmax over l ---- */
    if (tid < 64) {
        float mv = fmaxf(fmaxf(sp_sh[tid], sp_sh[tid+64]), fmaxf(sp_sh[tid+128], sp_sh[tid+192]));
        #pragma unroll
        for (int off = 32; off > 0; off >>= 1) mv = fmaxf(mv, __shfl_down(mv, off));
        if (tid == 0) scal_sh[0] = mv;
    }
    __syncthreads();
    {
        float mx = scal_sh[0];
        float sm = sp_sh[tid];
        float ev = (tid < 200) ? __expf(sm - mx) : 0.0f;
        sp_sh[tid] = ev;
    }
    __syncthreads();
    if (tid < 64) {
        float s = (sp_sh[tid] + sp_sh[tid+64]) + (sp_sh[tid+128] + sp_sh[tid+192]);
        #pragma unroll
        for (int off = 32; off > 0; off >>= 1) s += __shfl_down(s, off);
        if (tid == 0) scal_sh[1] = s;
    }
    __syncthreads();

    /* ---- Phase 4: pooling att (unnormalized) and ubs from bf16 Xc ---- */
    {
        int j = tid & 63, qq = tid >> 6;
        float accA = 0.f, accU = 0.f;
        int swzbase = (j >> 3);
        int inslot  = (j & 7) << 1;
        #pragma unroll 10
        for (int mm = qq*50; mm < qq*50 + 50; ++mm) {
            int byteoff = mm*128 + (((swzbase ^ (mm & 7)) << 4)) + inslot;
            float bv = bf2f(*(const u16*)((const char*)Xc + byteoff));
            accA += sp_sh[mm] * bv;
            accU += bv;
        }
        redA[tid] = accA;
        redU[tid] = accU;
    }
    __syncthreads();

    /* ---- write feature row X[b][288] ---- */
    float inv = 1.0f / scal_sh[1];
    if (tid < 64) {
        float att = ((redA[tid] + redA[tid+64]) + (redA[tid+128] + redA[tid+192])) * inv;
        float ub  =  (redU[tid] + redU[tid+64]) + (redU[tid+128] + redU[tid+192]);
        float qv  = q_sh[tid];
        float* xr = Xg + (size_t)b*288;
        xr[32  + tid] = qv;
        xr[96  + tid] = ub;
        xr[160 + tid] = ub * qv;
        xr[224 + tid] = att;
    }
    if (tid >= 64 && tid < 96) {
        Xg[(size_t)b*288 + (tid - 64)] = user_emb[(size_t)uid[b]*32 + (tid - 64)];
    }
}

/* ---- Kernel B: final MLP 288 -> 200 -> 80 -> 2 as row-tiled GEMM, f32 ---- */
__global__ __launch_bounds__(256) void mlp_kernel(
    const float* __restrict__ ws,
    const float* __restrict__ mlp_b1, const float* __restrict__ mlp_b2, const float* __restrict__ mlp_b3,
    const float* __restrict__ pa1, const float* __restrict__ pa2,
    float* __restrict__ out)
{
    __shared__ float h1_sh[16*204];
    __shared__ float h2_sh[16*81];

    const int tid = threadIdx.x;
    const int r0  = blockIdx.x * 16;
    const float* Xg  = ws + WS_XF;
    const float* w1T = ws + WS_W1T;
    const float* w2T = ws + WS_W2T;
    const float* w3T = ws + WS_W3T;

    /* layer 1: thread = neuron n, register-block over 16 rows; X rows read as uniform
       (scalar) loads, weights coalesced across threads */
    {
        int n = (tid < 200) ? tid : 199;
        float bias = mlp_b1[n];
        float acc[16];
        #pragma unroll
        for (int r = 0; r < 16; ++r) acc[r] = bias;
        for (int k = 0; k < 288; k += 4) {
            float w0 = w1T[(k+0)*200 + n];
            float w1 = w1T[(k+1)*200 + n];
            float w2 = w1T[(k+2)*200 + n];
            float w3 = w1T[(k+3)*200 + n];
            #pragma unroll
            for (int r = 0; r < 16; ++r) {
                const float4 xv = *(const float4*)(Xg + (size_t)(r0 + r)*288 + k);
                acc[r] += xv.x*w0 + xv.y*w1 + xv.z*w2 + xv.w*w3;
            }
        }
        if (tid < 200) {
            float a = pa1[n];
            #pragma unroll
            for (int r = 0; r < 16; ++r) {
                float v = acc[r];
                h1_sh[r*204 + n] = (v >= 0.f) ? v : a*v;
            }
        }
    }
    __syncthreads();

    /* layer 2: 160 active threads: g = tid%80, row-half = tid/80 (8 rows each) */
    if (tid < 160) {
        int g  = (tid < 80) ? tid : tid - 80;
        int rh = (tid < 80) ? 0 : 8;
        float bias = mlp_b2[g];
        float acc[8];
        #pragma unroll
        for (int r = 0; r < 8; ++r) acc[r] = bias;
        for (int k = 0; k < 200; k += 4) {
            float w0 = w2T[(k+0)*80 + g];
            float w1 = w2T[(k+1)*80 + g];
            float w2 = w2T[(k+2)*80 + g];
            float w3 = w2T[(k+3)*80 + g];
            #pragma unroll
            for (int r = 0; r < 8; ++r) {
                const float4 xv = *(const float4*)(&h1_sh[(rh + r)*204 + k]);
                acc[r] += xv.x*w0 + xv.y*w1 + xv.z*w2 + xv.w*w3;
            }
        }
        float a = pa2[g];
        #pragma unroll
        for (int r = 0; r < 8; ++r) {
            float v = acc[r];
            h2_sh[(rh + r)*81 + g] = (v >= 0.f) ? v : a*v;
        }
    }
    __syncthreads();

    /* layer 3: 32 threads: (row, o) */
    if (tid < 32) {
        int r = tid >> 1, o = tid & 1;
        float acc = mlp_b3[o];
        #pragma unroll 8
        for (int k = 0; k < 80; ++k) acc += h2_sh[r*81 + k] * w3T[k*2 + o];
        out[(size_t)(r0 + r)*2 + o] = acc;
    }
}

extern "C" void kernel_launch(void* const* d_in, const int* in_sizes, int n_in,
                              void* d_out, int out_size, void* d_ws, size_t ws_size,
                              hipStream_t stream) {
    const int*   uid      = (const int*)d_in[0];
    const int*   gid      = (const int*)d_in[1];
    const int*   cid      = (const int*)d_in[2];
    const int*   gid_his  = (const int*)d_in[3];
    const int*   cid_his  = (const int*)d_in[4];
    const int*   masks    = (const int*)d_in[5];
    const float* user_emb = (const float*)d_in[6];
    const float* good_emb = (const float*)d_in[7];
    const float* cat_emb  = (const float*)d_in[8];
    const float* att_w1   = (const float*)d_in[9];
    const float* att_b1   = (const float*)d_in[10];
    const float* att_w2   = (const float*)d_in[11];
    const float* att_b2   = (const float*)d_in[12];
    const float* att_w3   = (const float*)d_in[13];
    const float* att_b3   = (const float*)d_in[14];
    const float* mlp_w1   = (const float*)d_in[15];
    const float* mlp_b1   = (const float*)d_in[16];
    const float* mlp_w2   = (const float*)d_in[17];
    const float* mlp_b2   = (const float*)d_in[18];
    const float* mlp_w3   = (const float*)d_in[19];
    const float* mlp_b3   = (const float*)d_in[20];
    const float* pa1      = (const float*)d_in[21];
    const float* pa2      = (const float*)d_in[22];
    float* ws   = (float*)d_ws;
    float* outp = (float*)d_out;

    hipLaunchKernelGGL(prep_kernel, dim3(367), dim3(256), 0, stream,
                       att_w1, att_w2, att_w3, mlp_w1, mlp_w2, mlp_w3, ws);
    hipLaunchKernelGGL(din_kernel, dim3(4096), dim3(256), 0, stream,
                       uid, gid, cid, gid_his, cid_his, masks,
                       user_emb, good_emb, cat_emb,
                       att_b1, att_b2, att_b3,
                       ws, ws + WS_XF);
    hipLaunchKernelGGL(mlp_kernel, dim3(256), dim3(256), 0, stream,
                       ws, mlp_b1, mlp_b2, mlp_b3, pa1, pa2, outp);
}

// Round 5
// 188.679 us; speedup vs baseline: 5.3256x; 1.5027x over previous
//
#include <hip/hip_runtime.h>
#include <math.h>

typedef unsigned short u16;
typedef unsigned int u32;
typedef __attribute__((ext_vector_type(8))) short short8;
typedef __attribute__((ext_vector_type(8))) float f32x8;
typedef __attribute__((ext_vector_type(4))) float f32x4;
typedef __attribute__((ext_vector_type(2))) unsigned int uint2v;

#define NEG_BIG   (-4294967296.0f)   /* float32(-2^32+1) */
#define NEG_INF_F (-__builtin_inff())

/* ---- workspace layout (float offsets) ---- */
#define WS_S    0        /* [80][64] f32: w1[:,0:64]+w1[:,128:192] (for c0) */
#define WS_W1T  5120     /* [288][200] f32 mlp_w1^T */
#define WS_W2T  62720    /* [200][80]  f32 mlp_w2^T */
#define WS_W3T  78720    /* [80][2]    f32 mlp_w3^T */
#define WS_W3P  78880    /* [48] f32 att_w3 zero-padded */
#define WS_WF1F 78928    /* 10240 bf16 = 5120 float-slots: W1cat frags [5 nt][4 ks][64 lane][8] */
#define WS_WF2F 84048    /* 4608 bf16 = 2304 float-slots: W2cat frags [3 nt][3 ks][64 lane][8] */
#define WS_XF   86352    /* [4096][288] f32 feature rows (kernel A -> kernel B) */

__device__ __forceinline__ u16 f2bf(float f) {
    union { float f; u32 u; } v; v.f = f;
    u32 r = v.u + 0x7FFFu + ((v.u >> 16) & 1u);
    return (u16)(r >> 16);
}
__device__ __forceinline__ float bf2f(u16 h) {
    union { u32 u; float f; } v; v.u = ((u32)h) << 16;
    return v.f;
}
__device__ __forceinline__ float fsigmoid(float x) {
    return __fdividef(1.0f, 1.0f + __expf(-x));
}
__device__ __forceinline__ short8 mulqf(short8 a, f32x8 qf) {
    short8 r;
    #pragma unroll
    for (int j = 0; j < 8; ++j) r[j] = (short)f2bf(bf2f((u16)a[j]) * qf[j]);
    return r;
}
__device__ __forceinline__ f32x4 mfma16(short8 a, short8 b, f32x4 c) {
    return __builtin_amdgcn_mfma_f32_16x16x32_bf16(a, b, c, 0, 0, 0);
}

__global__ __launch_bounds__(256) void prep_kernel(
    const float* __restrict__ att_w1,
    const float* __restrict__ att_w2,
    const float* __restrict__ att_w3,
    const float* __restrict__ mlp_w1,
    const float* __restrict__ mlp_w2,
    const float* __restrict__ mlp_w3,
    float* __restrict__ ws)
{
    int idx = blockIdx.x * 256 + threadIdx.x;
    if (idx < 5120) {
        int h = idx >> 6, j = idx & 63;
        ws[WS_S + idx] = att_w1[h*256 + j] + att_w1[h*256 + 128 + j];
    } else if (idx < 62720) {
        int r = idx - 5120;            /* r = k*200 + t */
        int k = r / 200, t = r - k*200;
        ws[WS_W1T + r] = mlp_w1[t*288 + k];
    } else if (idx < 78720) {
        int r = idx - 62720;           /* r = k*80 + g */
        int k = r / 80, g = r - k*80;
        ws[WS_W2T + r] = mlp_w2[g*200 + k];
    } else if (idx < 78880) {
        int r = idx - 78720;           /* r = k*2 + o */
        int k = r >> 1, o = r & 1;
        ws[WS_W3T + r] = mlp_w3[o*80 + k];
    } else if (idx < 78928) {
        int g = idx - 78880;
        ws[WS_W3P + g] = (g < 40) ? att_w3[g] : 0.0f;
    } else if (idx < 89168) {
        /* W1cat fragments: Xcat(200x128) @ W1cat(128x80)
           k<64: beh rows -> w1[:,64:128]-w1[:,128:192]; k>=64: q*beh -> w1[:,192:256] */
        int e  = idx - 78928;
        int nt = e >> 11;
        int ks = (e >> 9) & 3;
        int ln = (e >> 3) & 63;
        int j  = e & 7;
        int n = nt*16 + (ln & 15);
        int k = ks*32 + (ln >> 4)*8 + j;
        float val = (k < 64)
            ? (att_w1[n*256 + 64 + k] - att_w1[n*256 + 128 + k])
            : att_w1[n*256 + 192 + (k - 64)];
        ((u16*)(ws + WS_WF1F))[e] = f2bf(val);
    } else if (idx < 93776) {
        /* W2cat fragments: S1(200x80,pad96) @ W2cat(96x48): W2cat[k][n]=att_w2[n*80+k] */
        int e  = idx - 89168;
        int nt = e / 1536;
        int ks = (e / 512) % 3;
        int ln = (e >> 3) & 63;
        int j  = e & 7;
        int n = nt*16 + (ln & 15);
        int k = ks*32 + (ln >> 4)*8 + j;
        float val = (n < 40 && k < 80) ? att_w2[n*80 + k] : 0.0f;
        ((u16*)(ws + WS_WF2F))[e] = f2bf(val);
    }
}

/* ---- Kernel A: gather + attention + softmax + pooling -> feature row X[b][288] ---- */
__global__ __launch_bounds__(256, 2) void din_kernel(
    const int* __restrict__ uid, const int* __restrict__ gid, const int* __restrict__ cid,
    const int* __restrict__ gid_his, const int* __restrict__ cid_his, const int* __restrict__ masks,
    const float* __restrict__ user_emb, const float* __restrict__ good_emb, const float* __restrict__ cat_emb,
    const float* __restrict__ att_b1, const float* __restrict__ att_b2, const float* __restrict__ att_b3,
    const float* __restrict__ ws, float* __restrict__ Xg)
{
    /* Xc[200 rows][64 bf16] with 16B-slot XOR swizzle: slot' = slot ^ (row&7)  (25600 B) */
    __shared__ u16 Xc[200*64];
    /* per-wave scratch: [16 rows][104 bf16] (row stride 208 B, 16B-aligned) */
    __shared__ u16 scr[4*1664];
    __shared__ float q_sh[64];
    __shared__ float c0_sh[80];
    __shared__ float sp_sh[256];
    __shared__ float scal_sh[2];

    /* overlays into scr (only live after the tile loop is done) */
    float* redA  = (float*)scr;       /* 256 */
    float* redU  = redA + 256;        /* 256 */

    const int b    = blockIdx.x;
    const int tid  = threadIdx.x;
    const int lane = tid & 63;
    const int wv   = tid >> 6;
    const int lrow = lane & 15;
    const int lgrp = lane >> 4;

    const int* gh = gid_his + b*200;
    const int* ch = cid_his + b*200;

    /* ---- Phase 0/1 fused: gather -> bf16 -> Xc (swizzled) ---- */
    #pragma unroll
    for (int it = 0; it < 12; ++it) {
        int idx = it*256 + tid;
        int l = idx >> 4, c = idx & 15;
        const float* src = (c < 8)
            ? (good_emb + (size_t)gh[l]*32 + (c & 7)*4)
            : (cat_emb  + (size_t)ch[l]*32 + (c & 7)*4);
        float4 v = *(const float4*)src;
        uint2v pk;
        pk[0] = (u32)f2bf(v.x) | ((u32)f2bf(v.y) << 16);
        pk[1] = (u32)f2bf(v.z) | ((u32)f2bf(v.w) << 16);
        int byteoff = l*128 + ((((c >> 1) ^ (l & 7)) << 4)) + ((c & 1) << 3);
        *((uint2v*)((char*)Xc + byteoff)) = pk;
    }
    if (tid < 128) {
        int idx = 3072 + tid;
        int l = idx >> 4, c = idx & 15;
        const float* src = (c < 8)
            ? (good_emb + (size_t)gh[l]*32 + (c & 7)*4)
            : (cat_emb  + (size_t)ch[l]*32 + (c & 7)*4);
        float4 v = *(const float4*)src;
        uint2v pk;
        pk[0] = (u32)f2bf(v.x) | ((u32)f2bf(v.y) << 16);
        pk[1] = (u32)f2bf(v.z) | ((u32)f2bf(v.w) << 16);
        int byteoff = l*128 + ((((c >> 1) ^ (l & 7)) << 4)) + ((c & 1) << 3);
        *((uint2v*)((char*)Xc + byteoff)) = pk;
    }
    if (tid < 64) {
        q_sh[tid] = (tid < 32) ? good_emb[(size_t)gid[b]*32 + tid]
                               : cat_emb[(size_t)cid[b]*32 + (tid - 32)];
    }
    if (tid >= 200 && tid < 256) sp_sh[tid] = NEG_INF_F;
    __syncthreads();

    /* c0[h] = b1[h] + sum_j q_j*(W1[h,j]+W1[h,128+j]) */
    if (tid < 80) {
        const float* Sw = ws + WS_S + tid*64;
        float u0 = 0.f, u1 = 0.f;
        #pragma unroll
        for (int j = 0; j < 64; j += 2) {
            u0 += q_sh[j]   * Sw[j];
            u1 += q_sh[j+1] * Sw[j+1];
        }
        c0_sh[tid] = att_b1[tid] + u0 + u1;
    }
    __syncthreads();

    /* ---- Phase 2: per-M-tile attention MLP via MFMA ---- */
    f32x8 qf0, qf1;
    #pragma unroll
    for (int j = 0; j < 8; ++j) {
        qf0[j] = q_sh[lgrp*8 + j];
        qf1[j] = q_sh[32 + lgrp*8 + j];
    }
    float c0v[5];
    #pragma unroll
    for (int nt = 0; nt < 5; ++nt) c0v[nt] = c0_sh[nt*16 + lrow];
    float b2v[3];
    #pragma unroll
    for (int nt = 0; nt < 3; ++nt) {
        int col = nt*16 + lrow;
        b2v[nt] = (col < 40) ? att_b2[col] : 0.0f;
    }
    const float bias3 = att_b3[0];

    const short8* WF1 = (const short8*)(ws + WS_WF1F);
    const short8* WF2 = (const short8*)(ws + WS_WF2F);
    u16*   scr_w = scr + wv*1664;
    float* scr_f = (float*)scr_w;

    for (int t = wv; t < 13; t += 4) {
        const int m0 = (t == 12) ? 184 : (t << 4);   /* tile 12 overlaps tile 11: benign same-value race */
        const int m  = m0 + lrow;

        /* A fragments: beh (ks 0,1 from LDS), q*beh (ks 2,3 in-register) */
        short8 A0, A1;
        {
            int sl0 = (0 + lgrp) ^ (m & 7);
            int sl1 = (4 + lgrp) ^ (m & 7);
            A0 = *(const short8*)((const char*)Xc + m*128 + (sl0 << 4));
            A1 = *(const short8*)((const char*)Xc + m*128 + (sl1 << 4));
        }
        short8 A2 = mulqf(A0, qf0);
        short8 A3 = mulqf(A1, qf1);

        /* layer 1: S1(16x80) = sigmoid(Xcat @ W1cat + c0) -> scratch bf16 */
        #pragma unroll
        for (int nt = 0; nt < 5; ++nt) {
            f32x4 acc = {0.f, 0.f, 0.f, 0.f};
            acc = mfma16(A0, WF1[(nt*4 + 0)*64 + lane], acc);
            acc = mfma16(A1, WF1[(nt*4 + 1)*64 + lane], acc);
            acc = mfma16(A2, WF1[(nt*4 + 2)*64 + lane], acc);
            acc = mfma16(A3, WF1[(nt*4 + 3)*64 + lane], acc);
            #pragma unroll
            for (int r = 0; r < 4; ++r) {
                float s1v = fsigmoid(acc[r] + c0v[nt]);
                scr_w[(lgrp*4 + r)*104 + nt*16 + lrow] = f2bf(s1v);
            }
        }
        /* zero-pad S1 cols 80..95 (K pad for layer 2) */
        {
            uint2v z; z[0] = 0u; z[1] = 0u;
            *((uint2v*)(scr_w + lrow*104 + 80 + lgrp*4)) = z;
        }

        /* layer 2: S2(16x48) = sigmoid(S1 @ W2cat + b2) -> scratch f32 */
        short8 B0 = *(const short8*)(scr_w + lrow*104 +  0 + lgrp*8);
        short8 B1 = *(const short8*)(scr_w + lrow*104 + 32 + lgrp*8);
        short8 B2 = *(const short8*)(scr_w + lrow*104 + 64 + lgrp*8);
        #pragma unroll
        for (int nt = 0; nt < 3; ++nt) {
            f32x4 acc = {0.f, 0.f, 0.f, 0.f};
            acc = mfma16(B0, WF2[(nt*3 + 0)*64 + lane], acc);
            acc = mfma16(B1, WF2[(nt*3 + 1)*64 + lane], acc);
            acc = mfma16(B2, WF2[(nt*3 + 2)*64 + lane], acc);
            #pragma unroll
            for (int r = 0; r < 4; ++r) {
                float s2v = fsigmoid(acc[r] + b2v[nt]);
                scr_f[(lgrp*4 + r)*52 + nt*16 + lrow] = s2v;
            }
        }

        /* layer 3: s[row] = b3 + sum_g sigmoid2[row][g]*w3[g]; 4 lanes per row */
        float v3 = 0.f;
        #pragma unroll
        for (int i = 0; i < 10; ++i) {
            int g = lgrp + 4*i;
            v3 += scr_f[lrow*52 + g] * ws[WS_W3P + g];
        }
        v3 += __shfl_xor(v3, 16);
        v3 += __shfl_xor(v3, 32);
        if (lane < 16) {
            int mm = m0 + lane;
            float sval = v3 + bias3;
            int mk = masks[b*200 + mm];
            sp_sh[mm] = mk ? sval : NEG_BIG;
        }
    }
    __syncthreads();

    /* ---- Phase 3: masked softmax over l ---- */
    if (tid < 64) {
        float mv = fmaxf(fmaxf(sp_sh[tid], sp_sh[tid+64]), fmaxf(sp_sh[tid+128], sp_sh[tid+192]));
        #pragma unroll
        for (int off = 32; off > 0; off >>= 1) mv = fmaxf(mv, __shfl_down(mv, off));
        if (tid == 0) scal_sh[0] = mv;
    }
    __syncthreads();
    {
        float mx = scal_sh[0];
        float sm = sp_sh[tid];
        float ev = (tid < 200) ? __expf(sm - mx) : 0.0f;
        sp_sh[tid] = ev;
    }
    __syncthreads();
    if (tid < 64) {
        float s = (sp_sh[tid] + sp_sh[tid+64]) + (sp_sh[tid+128] + sp_sh[tid+192]);
        #pragma unroll
        for (int off = 32; off > 0; off >>= 1) s += __shfl_down(s, off);
        if (tid == 0) scal_sh[1] = s;
    }
    __syncthreads();

    /* ---- Phase 4: pooling att (unnormalized) and ubs from bf16 Xc ---- */
    {
        int j = tid & 63, qq = tid >> 6;
        float accA = 0.f, accU = 0.f;
        int swzbase = (j >> 3);
        int inslot  = (j & 7) << 1;
        #pragma unroll 10
        for (int mm = qq*50; mm < qq*50 + 50; ++mm) {
            int byteoff = mm*128 + (((swzbase ^ (mm & 7)) << 4)) + inslot;
            float bv = bf2f(*(const u16*)((const char*)Xc + byteoff));
            accA += sp_sh[mm] * bv;
            accU += bv;
        }
        redA[tid] = accA;
        redU[tid] = accU;
    }
    __syncthreads();

    /* ---- write feature row X[b][288] ---- */
    float inv = 1.0f / scal_sh[1];
    if (tid < 64) {
        float att = ((redA[tid] + redA[tid+64]) + (redA[tid+128] + redA[tid+192])) * inv;
        float ub  =  (redU[tid] + redU[tid+64]) + (redU[tid+128] + redU[tid+192]);
        float qv  = q_sh[tid];
        float* xr = Xg + (size_t)b*288;
        xr[32  + tid] = qv;
        xr[96  + tid] = ub;
        xr[160 + tid] = ub * qv;
        xr[224 + tid] = att;
    }
    if (tid >= 64 && tid < 96) {
        Xg[(size_t)b*288 + (tid - 64)] = user_emb[(size_t)uid[b]*32 + (tid - 64)];
    }
}

/* ---- Kernel B: final MLP 288 -> 200 -> 80 -> 2 as row-tiled GEMM, f32 ---- */
__global__ __launch_bounds__(256) void mlp_kernel(
    const float* __restrict__ ws,
    const float* __restrict__ mlp_b1, const float* __restrict__ mlp_b2, const float* __restrict__ mlp_b3,
    const float* __restrict__ pa1, const float* __restrict__ pa2,
    float* __restrict__ out)
{
    __shared__ float h1_sh[16*204];
    __shared__ float h2_sh[16*81];

    const int tid = threadIdx.x;
    const int r0  = blockIdx.x * 16;
    const float* Xg  = ws + WS_XF;
    const float* w1T = ws + WS_W1T;
    const float* w2T = ws + WS_W2T;
    const float* w3T = ws + WS_W3T;

    /* layer 1: thread = neuron n, register-block over 16 rows */
    {
        int n = (tid < 200) ? tid : 199;
        float bias = mlp_b1[n];
        float acc[16];
        #pragma unroll
        for (int r = 0; r < 16; ++r) acc[r] = bias;
        for (int k = 0; k < 288; k += 4) {
            float w0 = w1T[(k+0)*200 + n];
            float w1 = w1T[(k+1)*200 + n];
            float w2 = w1T[(k+2)*200 + n];
            float w3 = w1T[(k+3)*200 + n];
            #pragma unroll
            for (int r = 0; r < 16; ++r) {
                const float4 xv = *(const float4*)(Xg + (size_t)(r0 + r)*288 + k);
                acc[r] += xv.x*w0 + xv.y*w1 + xv.z*w2 + xv.w*w3;
            }
        }
        if (tid < 200) {
            float a = pa1[n];
            #pragma unroll
            for (int r = 0; r < 16; ++r) {
                float v = acc[r];
                h1_sh[r*204 + n] = (v >= 0.f) ? v : a*v;
            }
        }
    }
    __syncthreads();

    /* layer 2: 160 active threads: g = tid%80, row-half = tid/80 (8 rows each) */
    if (tid < 160) {
        int g  = (tid < 80) ? tid : tid - 80;
        int rh = (tid < 80) ? 0 : 8;
        float bias = mlp_b2[g];
        float acc[8];
        #pragma unroll
        for (int r = 0; r < 8; ++r) acc[r] = bias;
        for (int k = 0; k < 200; k += 4) {
            float w0 = w2T[(k+0)*80 + g];
            float w1 = w2T[(k+1)*80 + g];
            float w2 = w2T[(k+2)*80 + g];
            float w3 = w2T[(k+3)*80 + g];
            #pragma unroll
            for (int r = 0; r < 8; ++r) {
                const float4 xv = *(const float4*)(&h1_sh[(rh + r)*204 + k]);
                acc[r] += xv.x*w0 + xv.y*w1 + xv.z*w2 + xv.w*w3;
            }
        }
        float a = pa2[g];
        #pragma unroll
        for (int r = 0; r < 8; ++r) {
            float v = acc[r];
            h2_sh[(rh + r)*81 + g] = (v >= 0.f) ? v : a*v;
        }
    }
    __syncthreads();

    /* layer 3: 32 threads: (row, o) */
    if (tid < 32) {
        int r = tid >> 1, o = tid & 1;
        float acc = mlp_b3[o];
        #pragma unroll 8
        for (int k = 0; k < 80; ++k) acc += h2_sh[r*81 + k] * w3T[k*2 + o];
        out[(size_t)(r0 + r)*2 + o] = acc;
    }
}

extern "C" void kernel_launch(void* const* d_in, const int* in_sizes, int n_in,
                              void* d_out, int out_size, void* d_ws, size_t ws_size,
                              hipStream_t stream) {
    const int*   uid      = (const int*)d_in[0];
    const int*   gid      = (const int*)d_in[1];
    const int*   cid      = (const int*)d_in[2];
    const int*   gid_his  = (const int*)d_in[3];
    const int*   cid_his  = (const int*)d_in[4];
    const int*   masks    = (const int*)d_in[5];
    const float* user_emb = (const float*)d_in[6];
    const float* good_emb = (const float*)d_in[7];
    const float* cat_emb  = (const float*)d_in[8];
    const float* att_w1   = (const float*)d_in[9];
    const float* att_b1   = (const float*)d_in[10];
    const float* att_w2   = (const float*)d_in[11];
    const float* att_b2   = (const float*)d_in[12];
    const float* att_w3   = (const float*)d_in[13];
    const float* att_b3   = (const float*)d_in[14];
    const float* mlp_w1   = (const float*)d_in[15];
    const float* mlp_b1   = (const float*)d_in[16];
    const float* mlp_w2   = (const float*)d_in[17];
    const float* mlp_b2   = (const float*)d_in[18];
    const float* mlp_w3   = (const float*)d_in[19];
    const float* mlp_b3   = (const float*)d_in[20];
    const float* pa1      = (const float*)d_in[21];
    const float* pa2      = (const float*)d_in[22];
    float* ws   = (float*)d_ws;
    float* outp = (float*)d_out;

    hipLaunchKernelGGL(prep_kernel, dim3(367), dim3(256), 0, stream,
                       att_w1, att_w2, att_w3, mlp_w1, mlp_w2, mlp_w3, ws);
    hipLaunchKernelGGL(din_kernel, dim3(4096), dim3(256), 0, stream,
                       uid, gid, cid, gid_his, cid_his, masks,
                       user_emb, good_emb, cat_emb,
                       att_b1, att_b2, att_b3,
                       ws, ws + WS_XF);
    hipLaunchKernelGGL(mlp_kernel, dim3(256), dim3(256), 0, stream,
                       ws, mlp_b1, mlp_b2, mlp_b3, pa1, pa2, outp);
}